// Round 6
// baseline (253.187 us; speedup 1.0000x reference)
//
#include <hip/hip_runtime.h>
#include <hip/hip_bf16.h>

#define BB 4
#define SS 2048
#define DM 1024
#define DN 64

typedef short short8 __attribute__((ext_vector_type(8)));
typedef float f32x4 __attribute__((ext_vector_type(4)));
typedef unsigned short ushort;

__device__ __forceinline__ ushort f2bf(float f) {          // round-nearest-even
    union { float f; unsigned u; } v; v.f = f;
    unsigned r = v.u + 0x7fffu + ((v.u >> 16) & 1u);
    return (ushort)(r >> 16);
}
__device__ __forceinline__ ushort f2bf_t(float f) {        // truncate (weights only)
    union { float f; unsigned u; } v; v.f = f;
    return (ushort)(v.u >> 16);
}
__device__ __forceinline__ short8 cvt8_rtn(float4 a, float4 b) {
    ushort t[8] = { f2bf(a.x), f2bf(a.y), f2bf(a.z), f2bf(a.w),
                    f2bf(b.x), f2bf(b.y), f2bf(b.z), f2bf(b.w) };
    return *(short8*)t;
}
__device__ __forceinline__ short8 cvt8_trc(float4 a, float4 b) {
    ushort t[8] = { f2bf_t(a.x), f2bf_t(a.y), f2bf_t(a.z), f2bf_t(a.w),
                    f2bf_t(b.x), f2bf_t(b.y), f2bf_t(b.z), f2bf_t(b.w) };
    return *(short8*)t;
}

// ---------------------------------------------------------------------------
// proj: out = x @ w^T + b. Barrier-free; explicit register pipeline:
// A (fp32, HBM/L3) depth 4, B (fp32 w, L2-hot) depth 2, consumed oldest-first
// and reissued every chunk -> ~4KB always in flight per wave. w converted
// in-loop (trunc for B: uniform ~0.2% shrink, harmless through softmax).
// One wave = 16 rows x 64 cols x K=1024. 1536 waves.
// qp/kp row-major bf16 [8192][64]; vp transposed [4][64][2048].
// ---------------------------------------------------------------------------
__global__ __launch_bounds__(256) void proj_kernel(
    const float* __restrict__ q, const float* __restrict__ k, const float* __restrict__ v,
    const float* __restrict__ wq, const float* __restrict__ wk, const float* __restrict__ wvm,
    const float* __restrict__ bq, const float* __restrict__ bk, const float* __restrict__ bvp,
    ushort* __restrict__ qp, ushort* __restrict__ kp, ushort* __restrict__ vpT)
{
    const int tid   = threadIdx.x;
    const int wv_id = tid >> 6;
    const int lane  = tid & 63;
    const int l16   = lane & 15;
    const int quad  = lane >> 4;
    const int w     = blockIdx.x * 4 + wv_id;   // 0..1535 (512 per proj; 128 blocks/proj)
    const int proj  = w >> 9;
    const int m0    = (w & 511) << 4;

    const float* x    = (proj == 0) ? q  : (proj == 1) ? k  : v;
    const float* wm   = (proj == 0) ? wq : (proj == 1) ? wk : wvm;
    const float* bias = (proj == 0) ? bq : (proj == 1) ? bk : bvp;

    const float* arow = x + (size_t)(m0 + l16) * DM + quad * 8;
    const float* brow0 = wm + (size_t)(l16     ) * DM + quad * 8;
    const float* brow1 = wm + (size_t)(l16 + 16) * DM + quad * 8;
    const float* brow2 = wm + (size_t)(l16 + 32) * DM + quad * 8;
    const float* brow3 = wm + (size_t)(l16 + 48) * DM + quad * 8;

    float4 apf[4][2];
    float4 bpf[2][4][2];
#pragma unroll
    for (int i = 0; i < 4; i++) {
        apf[i][0] = *(const float4*)(arow + i * 32);
        apf[i][1] = *(const float4*)(arow + i * 32 + 4);
    }
#pragma unroll
    for (int i = 0; i < 2; i++) {
        bpf[i][0][0] = *(const float4*)(brow0 + i * 32);
        bpf[i][0][1] = *(const float4*)(brow0 + i * 32 + 4);
        bpf[i][1][0] = *(const float4*)(brow1 + i * 32);
        bpf[i][1][1] = *(const float4*)(brow1 + i * 32 + 4);
        bpf[i][2][0] = *(const float4*)(brow2 + i * 32);
        bpf[i][2][1] = *(const float4*)(brow2 + i * 32 + 4);
        bpf[i][3][0] = *(const float4*)(brow3 + i * 32);
        bpf[i][3][1] = *(const float4*)(brow3 + i * 32 + 4);
    }

    f32x4 acc[4];
#pragma unroll
    for (int t = 0; t < 4; t++) acc[t] = (f32x4){0.f, 0.f, 0.f, 0.f};

#pragma unroll
    for (int c = 0; c < 32; c++) {
        const int ai = c & 3, bi = c & 1;
        short8 a  = cvt8_rtn(apf[ai][0], apf[ai][1]);
        short8 b0 = cvt8_trc(bpf[bi][0][0], bpf[bi][0][1]);
        short8 b1 = cvt8_trc(bpf[bi][1][0], bpf[bi][1][1]);
        short8 b2 = cvt8_trc(bpf[bi][2][0], bpf[bi][2][1]);
        short8 b3 = cvt8_trc(bpf[bi][3][0], bpf[bi][3][1]);
        acc[0] = __builtin_amdgcn_mfma_f32_16x16x32_bf16(a, b0, acc[0], 0, 0, 0);
        acc[1] = __builtin_amdgcn_mfma_f32_16x16x32_bf16(a, b1, acc[1], 0, 0, 0);
        acc[2] = __builtin_amdgcn_mfma_f32_16x16x32_bf16(a, b2, acc[2], 0, 0, 0);
        acc[3] = __builtin_amdgcn_mfma_f32_16x16x32_bf16(a, b3, acc[3], 0, 0, 0);
        if (c + 4 < 32) {
            apf[ai][0] = *(const float4*)(arow + (c + 4) * 32);
            apf[ai][1] = *(const float4*)(arow + (c + 4) * 32 + 4);
        }
        if (c + 2 < 32) {
            const int kb = (c + 2) * 32;
            bpf[bi][0][0] = *(const float4*)(brow0 + kb);
            bpf[bi][0][1] = *(const float4*)(brow0 + kb + 4);
            bpf[bi][1][0] = *(const float4*)(brow1 + kb);
            bpf[bi][1][1] = *(const float4*)(brow1 + kb + 4);
            bpf[bi][2][0] = *(const float4*)(brow2 + kb);
            bpf[bi][2][1] = *(const float4*)(brow2 + kb + 4);
            bpf[bi][3][0] = *(const float4*)(brow3 + kb);
            bpf[bi][3][1] = *(const float4*)(brow3 + kb + 4);
        }
    }

    // epilogue: C/D layout col = t*16+l16, row = quad*4+r
#pragma unroll
    for (int t = 0; t < 4; t++) {
        int n = t * 16 + l16;
        float bb_ = bias[n];
#pragma unroll
        for (int r = 0; r < 4; r++) {
            int grow = m0 + quad * 4 + r;
            ushort h = f2bf(acc[t][r] + bb_);
            if (proj == 0)      qp[(size_t)grow * DN + n] = h;
            else if (proj == 1) kp[(size_t)grow * DN + n] = h;
            else {
                int bb = grow >> 11, ss = grow & 2047;
                vpT[((size_t)bb * DN + n) * SS + ss] = h;
            }
        }
    }
}

// ---------------------------------------------------------------------------
// flash: block = (batch, 16-q-group), 4 waves = 4 key-slices of 512 (8 tiles
// of 64). Per-wave rotating register prefetch (mask: 4x dwordx4 coalesced;
// K frags) -> no drain. Mask redistributed via wave-private LDS [16][68]f32
// (write 8-way-ish x4, read 2-way free). In-block combine over the 4 slices
// via LDS after ONE barrier -> no partial-O global traffic, no combine kernel.
// ---------------------------------------------------------------------------
__global__ __launch_bounds__(256, 2) void flash_kernel(
    const float* __restrict__ mask,
    const ushort* __restrict__ qp,
    const ushort* __restrict__ kp,
    const ushort* __restrict__ vpT,
    float* __restrict__ out)
{
    // per-wave region: mask [16][68]f32 (4352B) | p [16][72]u16 (2304B) = 6656B
    // after loop, region start aliased as O [16][64]f32 + ml [16][2]f32 (4224B)
    __shared__ __align__(16) char smem[4 * 6656];

    const int tid  = threadIdx.x;
    const int wv   = tid >> 6;
    const int lane = tid & 63;
    const int l16  = lane & 15;
    const int quad = lane >> 4;
    const int b    = blockIdx.x >> 7;
    const int qg   = blockIdx.x & 127;

    float*  maskb = (float*)(smem + wv * 6656);
    ushort* pbuf  = (ushort*)(smem + wv * 6656 + 4352);

    const int k_begin = wv * 512;        // slice = wave id; 8 tiles of 64

    // Q fragments (A-layout), one-time
    const ushort* qbase = qp + ((size_t)b * SS + qg * 16 + l16) * DN + quad * 8;
    short8 aq0 = *(const short8*)(qbase);
    short8 aq1 = *(const short8*)(qbase + 32);

    // coalesced mask prefetch: lane -> (row = lane>>2, 16B segment = lane&3)
    const int mrow = lane >> 2;
    const int mseg = lane & 3;
    const float* mg = mask + ((size_t)b * SS + qg * 16 + mrow) * SS + mseg * 4;
    float4 mpf[4];
#pragma unroll
    for (int j = 0; j < 4; j++) mpf[j] = *(const float4*)(mg + k_begin + j * 16);

    short8 bk0[4], bk1[4];
#pragma unroll
    for (int t = 0; t < 4; t++) {
        const ushort* p_ = kp + ((size_t)b * SS + k_begin + t * 16 + l16) * DN + quad * 8;
        bk0[t] = *(const short8*)p_;
        bk1[t] = *(const short8*)(p_ + 32);
    }

    float m_r[4] = { -__builtin_inff(), -__builtin_inff(),
                     -__builtin_inff(), -__builtin_inff() };
    float l_r[4] = { 0.f, 0.f, 0.f, 0.f };
    f32x4 Oacc[4];
#pragma unroll
    for (int t = 0; t < 4; t++) Oacc[t] = (f32x4){0.f, 0.f, 0.f, 0.f};

#pragma unroll
    for (int it = 0; it < 8; ++it) {
        const int k0 = k_begin + it * 64;

        // mask regs -> wave-private LDS, then refill regs for next tile
#pragma unroll
        for (int j = 0; j < 4; j++)
            *(float4*)(maskb + mrow * 68 + j * 16 + mseg * 4) = mpf[j];
        if (it < 7) {
#pragma unroll
            for (int j = 0; j < 4; j++) mpf[j] = *(const float4*)(mg + k0 + 64 + j * 16);
        }

        // V frags for current tile (consumed after softmax — latency shadowed)
        short8 bv0[4], bv1[4];
#pragma unroll
        for (int tf = 0; tf < 4; tf++) {
            const ushort* p_ = vpT + ((size_t)b * DN + tf * 16 + l16) * SS + k0 + quad * 8;
            bv0[tf] = *(const short8*)p_;
            bv1[tf] = *(const short8*)(p_ + 32);
        }

        // S = qp . kp^T (C layout: key = t*16+l16, qrow = quad*4+r)
        f32x4 sc[4];
#pragma unroll
        for (int t = 0; t < 4; t++) {
            f32x4 z = (f32x4){0.f, 0.f, 0.f, 0.f};
            z = __builtin_amdgcn_mfma_f32_16x16x32_bf16(aq0, bk0[t], z, 0, 0, 0);
            z = __builtin_amdgcn_mfma_f32_16x16x32_bf16(aq1, bk1[t], z, 0, 0, 0);
            sc[t] = z;
        }
        // refill K frags for next tile (WAR after consume; covered by softmax)
        if (it < 7) {
#pragma unroll
            for (int t = 0; t < 4; t++) {
                const ushort* p_ = kp + ((size_t)b * SS + k0 + 64 + t * 16 + l16) * DN + quad * 8;
                bk0[t] = *(const short8*)p_;
                bk1[t] = *(const short8*)(p_ + 32);
            }
        }

        // online softmax; fp32 mask from LDS (argmax decided by ~1e2 gaps)
#pragma unroll
        for (int r = 0; r < 4; r++) {
            const float* mrow_l = maskb + (quad * 4 + r) * 68;
            float s[4];
            float tmax = -__builtin_inff();
#pragma unroll
            for (int t = 0; t < 4; t++) {
                s[t] = sc[t][r] * 0.125f - 1e9f * mrow_l[t * 16 + l16];
                tmax = fmaxf(tmax, s[t]);
            }
#pragma unroll
            for (int off = 8; off >= 1; off >>= 1)
                tmax = fmaxf(tmax, __shfl_xor(tmax, off, 16));
            float mnew  = fmaxf(m_r[r], tmax);
            float alpha = __expf(m_r[r] - mnew);
            m_r[r] = mnew;
            float rs = 0.f;
#pragma unroll
            for (int t = 0; t < 4; t++) {
                float pv = __expf(s[t] - mnew);
                rs += pv;
                pbuf[(quad * 4 + r) * 72 + t * 16 + l16] = f2bf(pv);
            }
#pragma unroll
            for (int off = 8; off >= 1; off >>= 1)
                rs += __shfl_xor(rs, off, 16);
            l_r[r] = l_r[r] * alpha + rs;
#pragma unroll
            for (int tf = 0; tf < 4; tf++)
                Oacc[tf][r] *= alpha;
        }

        // P: C-layout -> A-layout via wave-private LDS (in-order DS pipe)
        short8 ap0 = *(const short8*)&pbuf[l16 * 72 + quad * 8];
        short8 ap1 = *(const short8*)&pbuf[l16 * 72 + 32 + quad * 8];
#pragma unroll
        for (int tf = 0; tf < 4; tf++) {
            Oacc[tf] = __builtin_amdgcn_mfma_f32_16x16x32_bf16(ap0, bv0[tf], Oacc[tf], 0, 0, 0);
            Oacc[tf] = __builtin_amdgcn_mfma_f32_16x16x32_bf16(ap1, bv1[tf], Oacc[tf], 0, 0, 0);
        }
    }

    // publish this slice's (O, m, l) into own region (aliases mask buffer;
    // all own reads are program-order earlier)
    float* Ob  = (float*)(smem + wv * 6656);
    float* mlb = (float*)(smem + wv * 6656 + 4096);
#pragma unroll
    for (int tf = 0; tf < 4; tf++)
#pragma unroll
        for (int r = 0; r < 4; r++)
            Ob[(quad * 4 + r) * 64 + tf * 16 + l16] = Oacc[tf][r];
    if (l16 == 0) {
#pragma unroll
        for (int r = 0; r < 4; r++) {
            mlb[(quad * 4 + r) * 2 + 0] = m_r[r];
            mlb[(quad * 4 + r) * 2 + 1] = l_r[r];
        }
    }
    __syncthreads();

    // in-block combine over 4 slices: 1024 outputs, 4 per thread
#pragma unroll
    for (int j = 0; j < 4; j++) {
        int idx = tid + j * 256;
        int qq = idx >> 6, nn = idx & 63;
        float ms[4], ls[4];
        float M = -__builtin_inff();
#pragma unroll
        for (int s = 0; s < 4; s++) {
            const float* ml_s = (const float*)(smem + s * 6656 + 4096);
            ms[s] = ml_s[qq * 2 + 0];
            ls[s] = ml_s[qq * 2 + 1];
            M = fmaxf(M, ms[s]);
        }
        float L = 0.f, accv = 0.f;
#pragma unroll
        for (int s = 0; s < 4; s++) {
            float e = __expf(ms[s] - M);
            L += e * ls[s];
            accv += e * ((const float*)(smem + s * 6656))[qq * 64 + nn];
        }
        out[((size_t)b * SS + qg * 16 + qq) * DN + nn] = accv / L;
    }
}

extern "C" void kernel_launch(void* const* d_in, const int* in_sizes, int n_in,
                              void* d_out, int out_size, void* d_ws, size_t ws_size,
                              hipStream_t stream) {
    const float* q    = (const float*)d_in[0];
    const float* k    = (const float*)d_in[1];
    const float* v    = (const float*)d_in[2];
    const float* mask = (const float*)d_in[3];
    const float* wq   = (const float*)d_in[4];
    const float* bq   = (const float*)d_in[5];
    const float* wk   = (const float*)d_in[6];
    const float* bk   = (const float*)d_in[7];
    const float* wv   = (const float*)d_in[8];
    const float* bv   = (const float*)d_in[9];
    float* out = (float*)d_out;

    char* p = (char*)d_ws;
    ushort* qp  = (ushort*)p;   p += (size_t)BB * SS * DN * 2;   // 1 MB
    ushort* kp  = (ushort*)p;   p += (size_t)BB * SS * DN * 2;   // 1 MB
    ushort* vpT = (ushort*)p;                                    // 1 MB

    proj_kernel<<<384, 256, 0, stream>>>(q, k, v, wq, wk, wv, bq, bk, bv, qp, kp, vpT);
    flash_kernel<<<BB * 128, 256, 0, stream>>>(mask, qp, kp, vpT, out);
}